// Round 3
// baseline (181.835 us; speedup 1.0000x reference)
//
#include <hip/hip_runtime.h>

#define NTOK 4096
#define DMODEL 512
#define DEMB 64
#define DCAT 576
#define NHEAD 8
#define DHEAD 64
#define QSCALE 0.18033688011112042f

typedef float f32x4 __attribute__((ext_vector_type(4)));
typedef short s16x8 __attribute__((ext_vector_type(8)));
typedef unsigned short u16;
typedef u16 u16x4 __attribute__((ext_vector_type(4)));
typedef u16 u16x8 __attribute__((ext_vector_type(8)));
typedef unsigned int u32;

__device__ __forceinline__ u16 f2bf(float f) {
  union { float f; unsigned u; } v; v.f = f;
  unsigned r = v.u + 0x7fffu + ((v.u >> 16) & 1u);
  return (u16)(r >> 16);
}

__device__ __forceinline__ u32 cvtpk_bf16(float lo, float hi) {
  u32 r;
  asm("v_cvt_pk_bf16_f32 %0, %1, %2" : "=v"(r) : "v"(lo), "v"(hi));
  return r;
}

__device__ __forceinline__ void gload16(const void* g, void* lds) {
  __builtin_amdgcn_global_load_lds((const __attribute__((address_space(1))) u32*)g,
                                   (__attribute__((address_space(3))) u32*)lds, 16, 0, 0);
}

__global__ void wtrans_kernel(const float* __restrict__ Wq, const float* __restrict__ Wk,
                              const float* __restrict__ Wv, const float* __restrict__ Wf1,
                              const float* __restrict__ Wf2,
                              u16* __restrict__ Tqkv, u16* __restrict__ Tf1, u16* __restrict__ Tf2) {
  __shared__ float tile[64][65];
  int w = blockIdx.z;
  const float* src; u16* dst; int Ksrc, Kdst;
  if (w == 0)      { src = Wq;  dst = Tqkv;              Ksrc = 576; Kdst = 576; }
  else if (w == 1) { src = Wk;  dst = Tqkv + 512 * 576;  Ksrc = 576; Kdst = 576; }
  else if (w == 2) { src = Wv;  dst = Tqkv + 1024 * 576; Ksrc = 512; Kdst = 576; }
  else if (w == 3) { src = Wf1; dst = Tf1;               Ksrc = 512; Kdst = 512; }
  else             { src = Wf2; dst = Tf2;               Ksrc = 512; Kdst = 512; }
  int kb = blockIdx.x * 64;
  if (kb >= Kdst) return;
  int nb = blockIdx.y * 64;
  int tid = threadIdx.x;
  #pragma unroll
  for (int i = 0; i < 16; ++i) {
    int idx = tid + i * 256;
    int r = idx >> 6, c = idx & 63;
    tile[r][c] = (kb + r < Ksrc) ? src[(size_t)(kb + r) * DMODEL + nb + c] : 0.0f;
  }
  __syncthreads();
  #pragma unroll
  for (int i = 0; i < 16; ++i) {
    int idx = tid + i * 256;
    int r = idx >> 6, c = idx & 63;
    dst[(size_t)(nb + r) * Kdst + kb + c] = f2bf(tile[c][r]);
  }
}

__global__ void lnx_kernel(const float* __restrict__ x, const float* __restrict__ g,
                           const float* __restrict__ b, float* __restrict__ xt,
                           u16* __restrict__ qkin) {
  int row = blockIdx.x * 4 + (threadIdx.x >> 6);
  int lane = threadIdx.x & 63;
  const float* xr = x + (size_t)row * DMODEL + lane * 8;
  float v[8];
  float4 a0 = *(const float4*)xr;
  float4 a1 = *(const float4*)(xr + 4);
  v[0]=a0.x; v[1]=a0.y; v[2]=a0.z; v[3]=a0.w; v[4]=a1.x; v[5]=a1.y; v[6]=a1.z; v[7]=a1.w;
  float s = 0.f, ss = 0.f;
  #pragma unroll
  for (int j = 0; j < 8; ++j) { s += v[j]; ss += v[j]*v[j]; }
  #pragma unroll
  for (int off = 32; off > 0; off >>= 1) { s += __shfl_xor(s, off); ss += __shfl_xor(ss, off); }
  float mu = s * (1.0f / DMODEL);
  float var = ss * (1.0f / DMODEL) - mu * mu;
  float rs = rsqrtf(var + 1e-5f);
  float4 g0 = *(const float4*)(g + lane * 8);
  float4 g1v = *(const float4*)(g + lane * 8 + 4);
  float4 b0 = *(const float4*)(b + lane * 8);
  float4 b1v = *(const float4*)(b + lane * 8 + 4);
  float gg[8] = {g0.x,g0.y,g0.z,g0.w,g1v.x,g1v.y,g1v.z,g1v.w};
  float bb[8] = {b0.x,b0.y,b0.z,b0.w,b1v.x,b1v.y,b1v.z,b1v.w};
  float o[8]; u16x8 ob;
  #pragma unroll
  for (int j = 0; j < 8; ++j) { o[j] = (v[j]-mu)*rs*gg[j] + bb[j]; ob[j] = f2bf(o[j]); }
  float* xo = xt + (size_t)row * DMODEL + lane * 8;
  *(float4*)xo = make_float4(o[0],o[1],o[2],o[3]);
  *(float4*)(xo + 4) = make_float4(o[4],o[5],o[6],o[7]);
  *(u16x8*)(qkin + (size_t)row * DCAT + lane * 8) = ob;
}

__global__ void lne_kernel(const float* __restrict__ e, const float* __restrict__ g,
                           const float* __restrict__ b, u16* __restrict__ qkin) {
  int row = blockIdx.x * 4 + (threadIdx.x >> 6);
  int lane = threadIdx.x & 63;
  float v = e[(size_t)row * DEMB + lane];
  float s = v, ss = v * v;
  #pragma unroll
  for (int off = 32; off > 0; off >>= 1) { s += __shfl_xor(s, off); ss += __shfl_xor(ss, off); }
  float mu = s * (1.0f / DEMB);
  float var = ss * (1.0f / DEMB) - mu * mu;
  float rs = rsqrtf(var + 1e-5f);
  float o = (v - mu) * rs * g[lane] + b[lane];
  qkin[(size_t)row * DCAT + DMODEL + lane] = f2bf(o);
}

__global__ void ln3_kernel(const float* __restrict__ xt, const float* __restrict__ g,
                           const float* __restrict__ b, u16* __restrict__ hb) {
  int row = blockIdx.x * 4 + (threadIdx.x >> 6);
  int lane = threadIdx.x & 63;
  const float* xr = xt + (size_t)row * DMODEL + lane * 8;
  float v[8];
  float4 a0 = *(const float4*)xr;
  float4 a1 = *(const float4*)(xr + 4);
  v[0]=a0.x; v[1]=a0.y; v[2]=a0.z; v[3]=a0.w; v[4]=a1.x; v[5]=a1.y; v[6]=a1.z; v[7]=a1.w;
  float s = 0.f, ss = 0.f;
  #pragma unroll
  for (int j = 0; j < 8; ++j) { s += v[j]; ss += v[j]*v[j]; }
  #pragma unroll
  for (int off = 32; off > 0; off >>= 1) { s += __shfl_xor(s, off); ss += __shfl_xor(ss, off); }
  float mu = s * (1.0f / DMODEL);
  float var = ss * (1.0f / DMODEL) - mu * mu;
  float rs = rsqrtf(var + 1e-5f);
  float4 g0 = *(const float4*)(g + lane * 8);
  float4 g1v = *(const float4*)(g + lane * 8 + 4);
  float4 b0 = *(const float4*)(b + lane * 8);
  float4 b1v = *(const float4*)(b + lane * 8 + 4);
  float gg[8] = {g0.x,g0.y,g0.z,g0.w,g1v.x,g1v.y,g1v.z,g1v.w};
  float bb[8] = {b0.x,b0.y,b0.z,b0.w,b1v.x,b1v.y,b1v.z,b1v.w};
  u16x8 ob;
  #pragma unroll
  for (int j = 0; j < 8; ++j) ob[j] = f2bf((v[j]-mu)*rs*gg[j] + bb[j]);
  *(u16x8*)(hb + (size_t)row * DMODEL + lane * 8) = ob;
}

// BM=64, BN=64, BK=64, 4 waves (2x2). MODE 0: fused QKV (outb = qhd base;
// khd at +NTOK*DMODEL, vT at +2*NTOK*DMODEL). MODE 3: FFN1. MODE 4: FFN2.
template<int MODE>
__global__ __launch_bounds__(256) void gemm_kernel(
    const u16* __restrict__ A, int lda, const u16* __restrict__ Bt, int K,
    u16* __restrict__ outb, float* __restrict__ outf,
    const float* __restrict__ bias, const float* __restrict__ xt) {
  __shared__ __align__(16) u16 smem[8192];  // A 4096 elems + B 4096 elems
  u16* Al = smem;
  u16* Bl = smem + 4096;
  int tid = threadIdx.x, lane = tid & 63, wid = tid >> 6;
  int li = lane & 15, g4 = lane >> 4;
  int n0 = blockIdx.x * 64, m0 = blockIdx.y * 64;
  int wr = (wid >> 1) * 32, wc = (wid & 1) * 32;
  f32x4 acc[2][2] = {};
  for (int k0 = 0; k0 < K; k0 += 64) {
    #pragma unroll
    for (int i = 0; i < 2; ++i) {
      int idx = i * 256 + tid;
      int row = idx >> 3, cb = (idx & 7) * 8;
      gload16(A + (size_t)(m0 + row) * lda + k0 + cb, (char*)Al + idx * 16);
    }
    #pragma unroll
    for (int i = 0; i < 2; ++i) {
      int idx = i * 256 + tid;
      int row = idx >> 3, cb = (idx & 7) * 8;
      gload16(Bt + (size_t)(n0 + row) * K + k0 + cb, (char*)Bl + idx * 16);
    }
    __syncthreads();
    #pragma unroll
    for (int kk = 0; kk < 2; ++kk) {
      s16x8 af[2], bfv[2];
      #pragma unroll
      for (int mi = 0; mi < 2; ++mi)
        af[mi] = *(const s16x8*)&Al[(wr + mi * 16 + li) * 64 + kk * 32 + g4 * 8];
      #pragma unroll
      for (int ni = 0; ni < 2; ++ni)
        bfv[ni] = *(const s16x8*)&Bl[(wc + ni * 16 + li) * 64 + kk * 32 + g4 * 8];
      #pragma unroll
      for (int mi = 0; mi < 2; ++mi)
        #pragma unroll
        for (int ni = 0; ni < 2; ++ni)
          acc[mi][ni] = __builtin_amdgcn_mfma_f32_16x16x32_bf16(af[mi], bfv[ni], acc[mi][ni], 0, 0, 0);
    }
    __syncthreads();
  }
  if (MODE == 0) {
    if (n0 < 1024) {
      float scale = (n0 < 512) ? QSCALE : 1.0f;
      int nb = (n0 < 512) ? n0 : n0 - 512;
      u16* dst = outb + ((n0 < 512) ? 0 : (size_t)NTOK * DMODEL);
      #pragma unroll
      for (int mi = 0; mi < 2; ++mi)
        #pragma unroll
        for (int ni = 0; ni < 2; ++ni) {
          int col = nb + wc + ni * 16 + li;
          int h = col >> 6, dh = col & 63;
          #pragma unroll
          for (int r = 0; r < 4; ++r) {
            int row = m0 + wr + mi * 16 + g4 * 4 + r;
            dst[((size_t)h * NTOK + row) * DHEAD + dh] = f2bf(acc[mi][ni][r] * scale);
          }
        }
    } else {
      u16* vT = outb + (size_t)2 * NTOK * DMODEL;
      u16* tp = smem;  // [64][80]
      __syncthreads();
      #pragma unroll
      for (int mi = 0; mi < 2; ++mi)
        #pragma unroll
        for (int ni = 0; ni < 2; ++ni) {
          int cl = wc + ni * 16 + li;
          int r0 = wr + mi * 16 + g4 * 4;
          u16x4 pk;
          pk[0] = f2bf(acc[mi][ni][0]); pk[1] = f2bf(acc[mi][ni][1]);
          pk[2] = f2bf(acc[mi][ni][2]); pk[3] = f2bf(acc[mi][ni][3]);
          *(u16x4*)&tp[cl * 80 + r0] = pk;
        }
      __syncthreads();
      for (int c = tid; c < 512; c += 256) {
        int cl = c >> 3, seg = c & 7;
        u16x8 v = *(const u16x8*)&tp[cl * 80 + seg * 8];
        *(u16x8*)&vT[(size_t)(n0 - 1024 + cl) * NTOK + m0 + seg * 8] = v;
      }
    }
  } else {
    #pragma unroll
    for (int mi = 0; mi < 2; ++mi)
      #pragma unroll
      for (int ni = 0; ni < 2; ++ni) {
        int col = n0 + wc + ni * 16 + li;
        float bv = bias[col];
        #pragma unroll
        for (int r = 0; r < 4; ++r) {
          int row = m0 + wr + mi * 16 + g4 * 4 + r;
          float v = acc[mi][ni][r] + bv;
          if (MODE == 3) {
            v = fmaxf(v, 0.0f);
            outb[(size_t)row * DMODEL + col] = f2bf(v);
          } else {
            outf[(size_t)row * DMODEL + col] = v + xt[(size_t)row * DMODEL + col];
          }
        }
      }
  }
}

// fused flash attention v2 (fixed-max softmax: P = exp2(score), Q pre-scaled).
// grid 512: head = bid&7, qtile = bid>>3 (64 q rows). 8 waves = 2 q-groups x 4 key-splits.
__global__ __launch_bounds__(512, 4) void attn_kernel(
    const u16* __restrict__ qh, const u16* __restrict__ kh,
    const u16* __restrict__ vT, float* __restrict__ xt) {
  __shared__ __align__(16) u16 p_lds[8][2048];   // per wave [32 q][64 k] bf16 (XOR-swizzled)
  __shared__ float o_buf[2][2][32][65];
  __shared__ float l_lds[2][4][32];
  int tid = threadIdx.x, lane = tid & 63, wid = tid >> 6;
  int li = lane & 15, g4 = lane >> 4;
  int wq = wid >> 2, wk = wid & 3;
  int h = blockIdx.x & 7, qt = blockIdx.x >> 3;
  int q0 = qt * 64;
  const u16* qbase = qh + ((size_t)h * NTOK + q0 + wq * 32) * DHEAD;
  s16x8 bq[2][2];
  #pragma unroll
  for (int mi = 0; mi < 2; ++mi)
    #pragma unroll
    for (int kk = 0; kk < 2; ++kk)
      bq[mi][kk] = *(const s16x8*)(qbase + (mi * 16 + li) * DHEAD + kk * 32 + g4 * 8);
  f32x4 o[2][4] = {};
  float l_run[2] = {0.f, 0.f};
  char* pw = (char*)&p_lds[wid][0];
  const u16* kh_h = kh + (size_t)h * NTOK * DHEAD;
  const u16* v_h = vT + (size_t)(h * DHEAD) * NTOK;
  for (int t = 0; t < 16; ++t) {
    int kb = wk * 1024 + t * 64;
    const u16* kbase = kh_h + (size_t)kb * DHEAD;
    s16x8 ak[4][2];
    #pragma unroll
    for (int ni = 0; ni < 4; ++ni)
      #pragma unroll
      for (int kk = 0; kk < 2; ++kk)
        ak[ni][kk] = *(const s16x8*)(kbase + (ni * 16 + li) * DHEAD + kk * 32 + g4 * 8);
    #pragma unroll
    for (int mi = 0; mi < 2; ++mi) {
      f32x4 st[4];
      #pragma unroll
      for (int ni = 0; ni < 4; ++ni) {
        f32x4 z = {0.f, 0.f, 0.f, 0.f};
        z = __builtin_amdgcn_mfma_f32_16x16x32_bf16(ak[ni][0], bq[mi][0], z, 0, 0, 0);
        st[ni] = __builtin_amdgcn_mfma_f32_16x16x32_bf16(ak[ni][1], bq[mi][1], z, 0, 0, 0);
      }
      int rowoff = (mi * 16 + li) * 128;
      int swz = (li & 7) << 4;
      float rs = 0.f;
      #pragma unroll
      for (int ni = 0; ni < 4; ++ni) {
        float p0 = __builtin_amdgcn_exp2f(st[ni][0]);
        float p1 = __builtin_amdgcn_exp2f(st[ni][1]);
        float p2 = __builtin_amdgcn_exp2f(st[ni][2]);
        float p3 = __builtin_amdgcn_exp2f(st[ni][3]);
        rs += (p0 + p1) + (p2 + p3);
        uint2 pk;
        pk.x = cvtpk_bf16(p0, p1);
        pk.y = cvtpk_bf16(p2, p3);
        *(uint2*)(pw + rowoff + (((ni * 16 + g4 * 4) * 2) ^ swz)) = pk;
      }
      l_run[mi] += rs;
    }
    #pragma unroll
    for (int ki = 0; ki < 2; ++ki) {
      s16x8 ap[2], bv[4];
      #pragma unroll
      for (int mi = 0; mi < 2; ++mi)
        ap[mi] = *(const s16x8*)(pw + (mi * 16 + li) * 128 +
                                 (((ki * 32 + g4 * 8) * 2) ^ ((li & 7) << 4)));
      #pragma unroll
      for (int di = 0; di < 4; ++di)
        bv[di] = *(const s16x8*)(v_h + (size_t)(di * 16 + li) * NTOK + kb + ki * 32 + g4 * 8);
      #pragma unroll
      for (int mi = 0; mi < 2; ++mi)
        #pragma unroll
        for (int di = 0; di < 4; ++di)
          o[mi][di] = __builtin_amdgcn_mfma_f32_16x16x32_bf16(ap[mi], bv[di], o[mi][di], 0, 0, 0);
    }
  }
  #pragma unroll
  for (int mi = 0; mi < 2; ++mi) {
    float v = l_run[mi];
    v += __shfl_xor(v, 16);
    v += __shfl_xor(v, 32);
    if (g4 == 0) l_lds[wq][wk][mi * 16 + li] = v;
  }
  __syncthreads();
  if (wk < 2) {
    #pragma unroll
    for (int mi = 0; mi < 2; ++mi)
      #pragma unroll
      for (int di = 0; di < 4; ++di)
        #pragma unroll
        for (int r = 0; r < 4; ++r)
          o_buf[wq][wk][mi * 16 + g4 * 4 + r][di * 16 + li] = o[mi][di][r];
  }
  __syncthreads();
  if (wk >= 2) {
    #pragma unroll
    for (int mi = 0; mi < 2; ++mi)
      #pragma unroll
      for (int di = 0; di < 4; ++di)
        #pragma unroll
        for (int r = 0; r < 4; ++r)
          o_buf[wq][wk - 2][mi * 16 + g4 * 4 + r][di * 16 + li] += o[mi][di][r];
  }
  __syncthreads();
  int row = tid >> 3;
  int c8 = (tid & 7) * 8;
  int rq = row & 31, rw = row >> 5;
  float lt = l_lds[rw][0][rq] + l_lds[rw][1][rq] + l_lds[rw][2][rq] + l_lds[rw][3][rq];
  float rcp = 1.0f / lt;
  float* dst = xt + (size_t)(q0 + row) * DMODEL + h * DHEAD + c8;
  #pragma unroll
  for (int j = 0; j < 8; ++j)
    dst[j] += (o_buf[rw][0][rq][c8 + j] + o_buf[rw][1][rq][c8 + j]) * rcp;
}

extern "C" void kernel_launch(void* const* d_in, const int* in_sizes, int n_in,
                              void* d_out, int out_size, void* d_ws, size_t ws_size,
                              hipStream_t stream) {
  const float* x   = (const float*)d_in[0];
  const float* emb = (const float*)d_in[1];
  const float* Wq  = (const float*)d_in[2];
  const float* Wk  = (const float*)d_in[3];
  const float* Wv  = (const float*)d_in[4];
  const float* g1  = (const float*)d_in[5];
  const float* b1  = (const float*)d_in[6];
  const float* g2  = (const float*)d_in[7];
  const float* b2  = (const float*)d_in[8];
  const float* g3  = (const float*)d_in[9];
  const float* b3  = (const float*)d_in[10];
  const float* Wf1 = (const float*)d_in[11];
  const float* bf1 = (const float*)d_in[12];
  const float* Wf2 = (const float*)d_in[13];
  const float* bf2 = (const float*)d_in[14];
  float* out = (float*)d_out;

  char* ws = (char*)d_ws;
  size_t off = 0;
  auto alloc = [&](size_t bytes) { void* p = ws + off; off += (bytes + 255) & ~255ull; return p; };
  float* xt = (float*)alloc((size_t)NTOK * DMODEL * 4);
  u16* qkin = (u16*)alloc((size_t)NTOK * DCAT * 2);
  u16* hb   = (u16*)alloc((size_t)NTOK * DMODEL * 2);
  u16* r1   = (u16*)alloc((size_t)NTOK * DMODEL * 2);
  u16* qkvh = (u16*)alloc((size_t)3 * NTOK * DMODEL * 2);  // qhd | khd | vT contiguous
  u16* Tqkv = (u16*)alloc((size_t)1536 * DCAT * 2);
  u16* Tf1  = (u16*)alloc((size_t)DMODEL * DMODEL * 2);
  u16* Tf2  = (u16*)alloc((size_t)DMODEL * DMODEL * 2);
  u16* qhd = qkvh;
  u16* khd = qkvh + (size_t)NTOK * DMODEL;
  u16* vTd = qkvh + (size_t)2 * NTOK * DMODEL;

  wtrans_kernel<<<dim3(9, 8, 5), 256, 0, stream>>>(Wq, Wk, Wv, Wf1, Wf2, Tqkv, Tf1, Tf2);
  lnx_kernel<<<1024, 256, 0, stream>>>(x, g1, b1, xt, qkin);
  lne_kernel<<<1024, 256, 0, stream>>>(emb, g2, b2, qkin);
  gemm_kernel<0><<<dim3(24, 64), 256, 0, stream>>>(qkin, DCAT, Tqkv, DCAT, qkvh, nullptr, nullptr, nullptr);
  attn_kernel<<<512, 512, 0, stream>>>(qhd, khd, vTd, xt);
  ln3_kernel<<<1024, 256, 0, stream>>>(xt, g3, b3, hb);
  gemm_kernel<3><<<dim3(8, 64), 256, 0, stream>>>(hb, DMODEL, Tf1, DMODEL, r1, nullptr, bf1, nullptr);
  gemm_kernel<4><<<dim3(8, 64), 256, 0, stream>>>(r1, DMODEL, Tf2, DMODEL, nullptr, out, bf2, xt);
}

// Round 4
// 180.709 us; speedup vs baseline: 1.0062x; 1.0062x over previous
//
#include <hip/hip_runtime.h>

#define NTOK 4096
#define DMODEL 512
#define DEMB 64
#define DCAT 576
#define NHEAD 8
#define DHEAD 64
#define QSCALE 0.18033688011112042f  // (1/8) * log2(e)

typedef float f32x4 __attribute__((ext_vector_type(4)));
typedef short s16x8 __attribute__((ext_vector_type(8)));
typedef unsigned short u16;
typedef u16 u16x4 __attribute__((ext_vector_type(4)));
typedef u16 u16x8 __attribute__((ext_vector_type(8)));
typedef unsigned int u32;

__device__ __forceinline__ u16 f2bf(float f) {
  union { float f; unsigned u; } v; v.f = f;
  unsigned r = v.u + 0x7fffu + ((v.u >> 16) & 1u);
  return (u16)(r >> 16);
}

__device__ __forceinline__ u32 cvtpk_bf16(float lo, float hi) {
  u32 r;
  asm("v_cvt_pk_bf16_f32 %0, %1, %2" : "=v"(r) : "v"(lo), "v"(hi));
  return r;
}

__device__ __forceinline__ void gload16(const void* g, void* lds) {
  __builtin_amdgcn_global_load_lds((const __attribute__((address_space(1))) u32*)g,
                                   (__attribute__((address_space(3))) u32*)lds, 16, 0, 0);
}

__global__ void wtrans_kernel(const float* __restrict__ Wq, const float* __restrict__ Wk,
                              const float* __restrict__ Wv, const float* __restrict__ Wf1,
                              const float* __restrict__ Wf2,
                              u16* __restrict__ Tqkv, u16* __restrict__ Tf1, u16* __restrict__ Tf2) {
  __shared__ float tile[64][65];
  int w = blockIdx.z;
  const float* src; u16* dst; int Ksrc, Kdst;
  if (w == 0)      { src = Wq;  dst = Tqkv;              Ksrc = 576; Kdst = 576; }
  else if (w == 1) { src = Wk;  dst = Tqkv + 512 * 576;  Ksrc = 576; Kdst = 576; }
  else if (w == 2) { src = Wv;  dst = Tqkv + 1024 * 576; Ksrc = 512; Kdst = 576; }
  else if (w == 3) { src = Wf1; dst = Tf1;               Ksrc = 512; Kdst = 512; }
  else             { src = Wf2; dst = Tf2;               Ksrc = 512; Kdst = 512; }
  int kb = blockIdx.x * 64;
  if (kb >= Kdst) return;
  int nb = blockIdx.y * 64;
  int tid = threadIdx.x;
  #pragma unroll
  for (int i = 0; i < 16; ++i) {
    int idx = tid + i * 256;
    int r = idx >> 6, c = idx & 63;
    tile[r][c] = (kb + r < Ksrc) ? src[(size_t)(kb + r) * DMODEL + nb + c] : 0.0f;
  }
  __syncthreads();
  #pragma unroll
  for (int i = 0; i < 16; ++i) {
    int idx = tid + i * 256;
    int r = idx >> 6, c = idx & 63;
    dst[(size_t)(nb + r) * Kdst + kb + c] = f2bf(tile[c][r]);
  }
}

__global__ void lnx_kernel(const float* __restrict__ x, const float* __restrict__ g,
                           const float* __restrict__ b, float* __restrict__ xt,
                           u16* __restrict__ qkin) {
  int row = blockIdx.x * 4 + (threadIdx.x >> 6);
  int lane = threadIdx.x & 63;
  const float* xr = x + (size_t)row * DMODEL + lane * 8;
  float v[8];
  float4 a0 = *(const float4*)xr;
  float4 a1 = *(const float4*)(xr + 4);
  v[0]=a0.x; v[1]=a0.y; v[2]=a0.z; v[3]=a0.w; v[4]=a1.x; v[5]=a1.y; v[6]=a1.z; v[7]=a1.w;
  float s = 0.f, ss = 0.f;
  #pragma unroll
  for (int j = 0; j < 8; ++j) { s += v[j]; ss += v[j]*v[j]; }
  #pragma unroll
  for (int off = 32; off > 0; off >>= 1) { s += __shfl_xor(s, off); ss += __shfl_xor(ss, off); }
  float mu = s * (1.0f / DMODEL);
  float var = ss * (1.0f / DMODEL) - mu * mu;
  float rs = rsqrtf(var + 1e-5f);
  float4 g0 = *(const float4*)(g + lane * 8);
  float4 g1v = *(const float4*)(g + lane * 8 + 4);
  float4 b0 = *(const float4*)(b + lane * 8);
  float4 b1v = *(const float4*)(b + lane * 8 + 4);
  float gg[8] = {g0.x,g0.y,g0.z,g0.w,g1v.x,g1v.y,g1v.z,g1v.w};
  float bb[8] = {b0.x,b0.y,b0.z,b0.w,b1v.x,b1v.y,b1v.z,b1v.w};
  float o[8]; u16x8 ob;
  #pragma unroll
  for (int j = 0; j < 8; ++j) { o[j] = (v[j]-mu)*rs*gg[j] + bb[j]; ob[j] = f2bf(o[j]); }
  float* xo = xt + (size_t)row * DMODEL + lane * 8;
  *(float4*)xo = make_float4(o[0],o[1],o[2],o[3]);
  *(float4*)(xo + 4) = make_float4(o[4],o[5],o[6],o[7]);
  *(u16x8*)(qkin + (size_t)row * DCAT + lane * 8) = ob;
}

__global__ void lne_kernel(const float* __restrict__ e, const float* __restrict__ g,
                           const float* __restrict__ b, u16* __restrict__ qkin) {
  int row = blockIdx.x * 4 + (threadIdx.x >> 6);
  int lane = threadIdx.x & 63;
  float v = e[(size_t)row * DEMB + lane];
  float s = v, ss = v * v;
  #pragma unroll
  for (int off = 32; off > 0; off >>= 1) { s += __shfl_xor(s, off); ss += __shfl_xor(ss, off); }
  float mu = s * (1.0f / DEMB);
  float var = ss * (1.0f / DEMB) - mu * mu;
  float rs = rsqrtf(var + 1e-5f);
  float o = (v - mu) * rs * g[lane] + b[lane];
  qkin[(size_t)row * DCAT + DMODEL + lane] = f2bf(o);
}

__global__ void ln3_kernel(const float* __restrict__ xt, const float* __restrict__ g,
                           const float* __restrict__ b, u16* __restrict__ hb) {
  int row = blockIdx.x * 4 + (threadIdx.x >> 6);
  int lane = threadIdx.x & 63;
  const float* xr = xt + (size_t)row * DMODEL + lane * 8;
  float v[8];
  float4 a0 = *(const float4*)xr;
  float4 a1 = *(const float4*)(xr + 4);
  v[0]=a0.x; v[1]=a0.y; v[2]=a0.z; v[3]=a0.w; v[4]=a1.x; v[5]=a1.y; v[6]=a1.z; v[7]=a1.w;
  float s = 0.f, ss = 0.f;
  #pragma unroll
  for (int j = 0; j < 8; ++j) { s += v[j]; ss += v[j]*v[j]; }
  #pragma unroll
  for (int off = 32; off > 0; off >>= 1) { s += __shfl_xor(s, off); ss += __shfl_xor(ss, off); }
  float mu = s * (1.0f / DMODEL);
  float var = ss * (1.0f / DMODEL) - mu * mu;
  float rs = rsqrtf(var + 1e-5f);
  float4 g0 = *(const float4*)(g + lane * 8);
  float4 g1v = *(const float4*)(g + lane * 8 + 4);
  float4 b0 = *(const float4*)(b + lane * 8);
  float4 b1v = *(const float4*)(b + lane * 8 + 4);
  float gg[8] = {g0.x,g0.y,g0.z,g0.w,g1v.x,g1v.y,g1v.z,g1v.w};
  float bb[8] = {b0.x,b0.y,b0.z,b0.w,b1v.x,b1v.y,b1v.z,b1v.w};
  u16x8 ob;
  #pragma unroll
  for (int j = 0; j < 8; ++j) ob[j] = f2bf((v[j]-mu)*rs*gg[j] + bb[j]);
  *(u16x8*)(hb + (size_t)row * DMODEL + lane * 8) = ob;
}

// BM=64, BN=64, BK=64, 4 waves (2x2). MODE 0: fused QKV (outb = qhd base;
// khd at +NTOK*DMODEL, vT at +2*NTOK*DMODEL). MODE 3: FFN1. MODE 4: FFN2.
template<int MODE>
__global__ __launch_bounds__(256) void gemm_kernel(
    const u16* __restrict__ A, int lda, const u16* __restrict__ Bt, int K,
    u16* __restrict__ outb, float* __restrict__ outf,
    const float* __restrict__ bias, const float* __restrict__ xt) {
  __shared__ __align__(16) u16 smem[8192];
  u16* Al = smem;
  u16* Bl = smem + 4096;
  int tid = threadIdx.x, lane = tid & 63, wid = tid >> 6;
  int li = lane & 15, g4 = lane >> 4;
  int n0 = blockIdx.x * 64, m0 = blockIdx.y * 64;
  int wr = (wid >> 1) * 32, wc = (wid & 1) * 32;
  f32x4 acc[2][2] = {};
  for (int k0 = 0; k0 < K; k0 += 64) {
    #pragma unroll
    for (int i = 0; i < 2; ++i) {
      int idx = i * 256 + tid;
      int row = idx >> 3, cb = (idx & 7) * 8;
      gload16(A + (size_t)(m0 + row) * lda + k0 + cb, (char*)Al + idx * 16);
    }
    #pragma unroll
    for (int i = 0; i < 2; ++i) {
      int idx = i * 256 + tid;
      int row = idx >> 3, cb = (idx & 7) * 8;
      gload16(Bt + (size_t)(n0 + row) * K + k0 + cb, (char*)Bl + idx * 16);
    }
    __syncthreads();
    #pragma unroll
    for (int kk = 0; kk < 2; ++kk) {
      s16x8 af[2], bfv[2];
      #pragma unroll
      for (int mi = 0; mi < 2; ++mi)
        af[mi] = *(const s16x8*)&Al[(wr + mi * 16 + li) * 64 + kk * 32 + g4 * 8];
      #pragma unroll
      for (int ni = 0; ni < 2; ++ni)
        bfv[ni] = *(const s16x8*)&Bl[(wc + ni * 16 + li) * 64 + kk * 32 + g4 * 8];
      #pragma unroll
      for (int mi = 0; mi < 2; ++mi)
        #pragma unroll
        for (int ni = 0; ni < 2; ++ni)
          acc[mi][ni] = __builtin_amdgcn_mfma_f32_16x16x32_bf16(af[mi], bfv[ni], acc[mi][ni], 0, 0, 0);
    }
    __syncthreads();
  }
  if (MODE == 0) {
    if (n0 < 1024) {
      float scale = (n0 < 512) ? QSCALE : 1.0f;
      int nb = (n0 < 512) ? n0 : n0 - 512;
      u16* dst = outb + ((n0 < 512) ? 0 : (size_t)NTOK * DMODEL);
      #pragma unroll
      for (int mi = 0; mi < 2; ++mi)
        #pragma unroll
        for (int ni = 0; ni < 2; ++ni) {
          int col = nb + wc + ni * 16 + li;
          int h = col >> 6, dh = col & 63;
          #pragma unroll
          for (int r = 0; r < 4; ++r) {
            int row = m0 + wr + mi * 16 + g4 * 4 + r;
            dst[((size_t)h * NTOK + row) * DHEAD + dh] = f2bf(acc[mi][ni][r] * scale);
          }
        }
    } else {
      u16* vT = outb + (size_t)2 * NTOK * DMODEL;
      u16* tp = smem;  // [64][80]
      __syncthreads();
      #pragma unroll
      for (int mi = 0; mi < 2; ++mi)
        #pragma unroll
        for (int ni = 0; ni < 2; ++ni) {
          int cl = wc + ni * 16 + li;
          int r0 = wr + mi * 16 + g4 * 4;
          u16x4 pk;
          pk[0] = f2bf(acc[mi][ni][0]); pk[1] = f2bf(acc[mi][ni][1]);
          pk[2] = f2bf(acc[mi][ni][2]); pk[3] = f2bf(acc[mi][ni][3]);
          *(u16x4*)&tp[cl * 80 + r0] = pk;
        }
      __syncthreads();
      for (int c = tid; c < 512; c += 256) {
        int cl = c >> 3, seg = c & 7;
        u16x8 v = *(const u16x8*)&tp[cl * 80 + seg * 8];
        *(u16x8*)&vT[(size_t)(n0 - 1024 + cl) * NTOK + m0 + seg * 8] = v;
      }
    }
  } else {
    #pragma unroll
    for (int mi = 0; mi < 2; ++mi)
      #pragma unroll
      for (int ni = 0; ni < 2; ++ni) {
        int col = n0 + wc + ni * 16 + li;
        float bv = bias[col];
        #pragma unroll
        for (int r = 0; r < 4; ++r) {
          int row = m0 + wr + mi * 16 + g4 * 4 + r;
          float v = acc[mi][ni][r] + bv;
          if (MODE == 3) {
            v = fmaxf(v, 0.0f);
            outb[(size_t)row * DMODEL + col] = f2bf(v);
          } else {
            outf[(size_t)row * DMODEL + col] = v + xt[(size_t)row * DMODEL + col];
          }
        }
      }
  }
}

// fused flash attention v3 (fixed-max softmax: P = exp2(score), Q pre-scaled).
// grid 1024: head = bid&7 (XCD/L2 locality), qtile = bid>>3 (32 q rows).
// 4 waves = 4 key-splits of 1024 keys each. 256 threads, VGPR cap 128.
__global__ __launch_bounds__(256, 4) void attn_kernel(
    const u16* __restrict__ qh, const u16* __restrict__ kh,
    const u16* __restrict__ vT, float* __restrict__ xt) {
  __shared__ __align__(16) u16 p_lds[4][2048];   // per wave [32 q][64 k] bf16 (XOR-swizzled)
  __shared__ float o_buf[2][32][65];
  __shared__ float l_lds[4][32];
  int tid = threadIdx.x, lane = tid & 63, wk = tid >> 6;
  int li = lane & 15, g4 = lane >> 4;
  int h = blockIdx.x & 7, qt = blockIdx.x >> 3;
  int q0 = qt * 32;
  const u16* qbase = qh + ((size_t)h * NTOK + q0) * DHEAD;
  s16x8 bq[2][2];
  #pragma unroll
  for (int mi = 0; mi < 2; ++mi)
    #pragma unroll
    for (int kk = 0; kk < 2; ++kk)
      bq[mi][kk] = *(const s16x8*)(qbase + (mi * 16 + li) * DHEAD + kk * 32 + g4 * 8);
  f32x4 o[2][4] = {};
  float l_run[2] = {0.f, 0.f};
  char* pw = (char*)&p_lds[wk][0];
  const u16* kh_h = kh + (size_t)h * NTOK * DHEAD;
  const u16* v_h = vT + (size_t)(h * DHEAD) * NTOK;
  for (int t = 0; t < 16; ++t) {
    int kb = wk * 1024 + t * 64;
    const u16* kbase = kh_h + (size_t)kb * DHEAD;
    s16x8 ak[4][2];
    #pragma unroll
    for (int ni = 0; ni < 4; ++ni)
      #pragma unroll
      for (int kk = 0; kk < 2; ++kk)
        ak[ni][kk] = *(const s16x8*)(kbase + (ni * 16 + li) * DHEAD + kk * 32 + g4 * 8);
    #pragma unroll
    for (int mi = 0; mi < 2; ++mi) {
      f32x4 st[4];
      #pragma unroll
      for (int ni = 0; ni < 4; ++ni) {
        f32x4 z = {0.f, 0.f, 0.f, 0.f};
        z = __builtin_amdgcn_mfma_f32_16x16x32_bf16(ak[ni][0], bq[mi][0], z, 0, 0, 0);
        st[ni] = __builtin_amdgcn_mfma_f32_16x16x32_bf16(ak[ni][1], bq[mi][1], z, 0, 0, 0);
      }
      int rowoff = (mi * 16 + li) * 128;
      int swz = (li & 7) << 4;
      float rs = 0.f;
      #pragma unroll
      for (int ni = 0; ni < 4; ++ni) {
        float p0 = __builtin_amdgcn_exp2f(st[ni][0]);
        float p1 = __builtin_amdgcn_exp2f(st[ni][1]);
        float p2 = __builtin_amdgcn_exp2f(st[ni][2]);
        float p3 = __builtin_amdgcn_exp2f(st[ni][3]);
        rs += (p0 + p1) + (p2 + p3);
        uint2 pk;
        pk.x = cvtpk_bf16(p0, p1);
        pk.y = cvtpk_bf16(p2, p3);
        *(uint2*)(pw + rowoff + (((ni * 16 + g4 * 4) * 2) ^ swz)) = pk;
      }
      l_run[mi] += rs;
    }
    #pragma unroll
    for (int ki = 0; ki < 2; ++ki) {
      s16x8 ap[2], bv[4];
      #pragma unroll
      for (int mi = 0; mi < 2; ++mi)
        ap[mi] = *(const s16x8*)(pw + (mi * 16 + li) * 128 +
                                 (((ki * 32 + g4 * 8) * 2) ^ ((li & 7) << 4)));
      #pragma unroll
      for (int di = 0; di < 4; ++di)
        bv[di] = *(const s16x8*)(v_h + (size_t)(di * 16 + li) * NTOK + kb + ki * 32 + g4 * 8);
      #pragma unroll
      for (int mi = 0; mi < 2; ++mi)
        #pragma unroll
        for (int di = 0; di < 4; ++di)
          o[mi][di] = __builtin_amdgcn_mfma_f32_16x16x32_bf16(ap[mi], bv[di], o[mi][di], 0, 0, 0);
    }
  }
  #pragma unroll
  for (int mi = 0; mi < 2; ++mi) {
    float v = l_run[mi];
    v += __shfl_xor(v, 16);
    v += __shfl_xor(v, 32);
    if (g4 == 0) l_lds[wk][mi * 16 + li] = v;
  }
  __syncthreads();
  if (wk < 2) {
    #pragma unroll
    for (int mi = 0; mi < 2; ++mi)
      #pragma unroll
      for (int di = 0; di < 4; ++di)
        #pragma unroll
        for (int r = 0; r < 4; ++r)
          o_buf[wk][mi * 16 + g4 * 4 + r][di * 16 + li] = o[mi][di][r];
  }
  __syncthreads();
  if (wk >= 2) {
    #pragma unroll
    for (int mi = 0; mi < 2; ++mi)
      #pragma unroll
      for (int di = 0; di < 4; ++di)
        #pragma unroll
        for (int r = 0; r < 4; ++r)
          o_buf[wk - 2][mi * 16 + g4 * 4 + r][di * 16 + li] += o[mi][di][r];
  }
  __syncthreads();
  int row = tid >> 3;
  int c8 = (tid & 7) * 8;
  float lt = l_lds[0][row] + l_lds[1][row] + l_lds[2][row] + l_lds[3][row];
  float rcp = 1.0f / lt;
  float* dst = xt + (size_t)(q0 + row) * DMODEL + h * DHEAD + c8;
  #pragma unroll
  for (int j = 0; j < 8; ++j)
    dst[j] += (o_buf[0][row][c8 + j] + o_buf[1][row][c8 + j]) * rcp;
}

extern "C" void kernel_launch(void* const* d_in, const int* in_sizes, int n_in,
                              void* d_out, int out_size, void* d_ws, size_t ws_size,
                              hipStream_t stream) {
  const float* x   = (const float*)d_in[0];
  const float* emb = (const float*)d_in[1];
  const float* Wq  = (const float*)d_in[2];
  const float* Wk  = (const float*)d_in[3];
  const float* Wv  = (const float*)d_in[4];
  const float* g1  = (const float*)d_in[5];
  const float* b1  = (const float*)d_in[6];
  const float* g2  = (const float*)d_in[7];
  const float* b2  = (const float*)d_in[8];
  const float* g3  = (const float*)d_in[9];
  const float* b3  = (const float*)d_in[10];
  const float* Wf1 = (const float*)d_in[11];
  const float* bf1 = (const float*)d_in[12];
  const float* Wf2 = (const float*)d_in[13];
  const float* bf2 = (const float*)d_in[14];
  float* out = (float*)d_out;

  char* ws = (char*)d_ws;
  size_t off = 0;
  auto alloc = [&](size_t bytes) { void* p = ws + off; off += (bytes + 255) & ~255ull; return p; };
  float* xt = (float*)alloc((size_t)NTOK * DMODEL * 4);
  u16* qkin = (u16*)alloc((size_t)NTOK * DCAT * 2);
  u16* hb   = (u16*)alloc((size_t)NTOK * DMODEL * 2);
  u16* r1   = (u16*)alloc((size_t)NTOK * DMODEL * 2);
  u16* qkvh = (u16*)alloc((size_t)3 * NTOK * DMODEL * 2);  // qhd | khd | vT contiguous
  u16* Tqkv = (u16*)alloc((size_t)1536 * DCAT * 2);
  u16* Tf1  = (u16*)alloc((size_t)DMODEL * DMODEL * 2);
  u16* Tf2  = (u16*)alloc((size_t)DMODEL * DMODEL * 2);
  u16* qhd = qkvh;
  u16* khd = qkvh + (size_t)NTOK * DMODEL;
  u16* vTd = qkvh + (size_t)2 * NTOK * DMODEL;

  wtrans_kernel<<<dim3(9, 8, 5), 256, 0, stream>>>(Wq, Wk, Wv, Wf1, Wf2, Tqkv, Tf1, Tf2);
  lnx_kernel<<<1024, 256, 0, stream>>>(x, g1, b1, xt, qkin);
  lne_kernel<<<1024, 256, 0, stream>>>(emb, g2, b2, qkin);
  gemm_kernel<0><<<dim3(24, 64), 256, 0, stream>>>(qkin, DCAT, Tqkv, DCAT, qkvh, nullptr, nullptr, nullptr);
  attn_kernel<<<1024, 256, 0, stream>>>(qhd, khd, vTd, xt);
  ln3_kernel<<<1024, 256, 0, stream>>>(xt, g3, b3, hb);
  gemm_kernel<3><<<dim3(8, 64), 256, 0, stream>>>(hb, DMODEL, Tf1, DMODEL, r1, nullptr, bf1, nullptr);
  gemm_kernel<4><<<dim3(8, 64), 256, 0, stream>>>(r1, DMODEL, Tf2, DMODEL, nullptr, out, bf2, xt);
}

// Round 5
// 179.056 us; speedup vs baseline: 1.0155x; 1.0092x over previous
//
#include <hip/hip_runtime.h>

#define NTOK 4096
#define DMODEL 512
#define DEMB 64
#define DCAT 576
#define NHEAD 8
#define DHEAD 64
#define QSCALE 0.18033688011112042f  // (1/8) * log2(e)

typedef float f32x4 __attribute__((ext_vector_type(4)));
typedef short s16x8 __attribute__((ext_vector_type(8)));
typedef unsigned short u16;
typedef u16 u16x4 __attribute__((ext_vector_type(4)));
typedef u16 u16x8 __attribute__((ext_vector_type(8)));
typedef unsigned int u32;

__device__ __forceinline__ u16 f2bf(float f) {
  union { float f; unsigned u; } v; v.f = f;
  unsigned r = v.u + 0x7fffu + ((v.u >> 16) & 1u);
  return (u16)(r >> 16);
}

__device__ __forceinline__ u32 cvtpk_bf16(float lo, float hi) {
  u32 r;
  asm("v_cvt_pk_bf16_f32 %0, %1, %2" : "=v"(r) : "v"(lo), "v"(hi));
  return r;
}

__device__ __forceinline__ void gload16(const void* g, void* lds) {
  __builtin_amdgcn_global_load_lds((const __attribute__((address_space(1))) u32*)g,
                                   (__attribute__((address_space(3))) u32*)lds, 16, 0, 0);
}

__global__ void wtrans_kernel(const float* __restrict__ Wq, const float* __restrict__ Wk,
                              const float* __restrict__ Wv, const float* __restrict__ Wf1,
                              const float* __restrict__ Wf2,
                              u16* __restrict__ Tqkv, u16* __restrict__ Tf1, u16* __restrict__ Tf2) {
  __shared__ float tile[64][65];
  int w = blockIdx.z;
  const float* src; u16* dst; int Ksrc, Kdst;
  if (w == 0)      { src = Wq;  dst = Tqkv;              Ksrc = 576; Kdst = 576; }
  else if (w == 1) { src = Wk;  dst = Tqkv + 512 * 576;  Ksrc = 576; Kdst = 576; }
  else if (w == 2) { src = Wv;  dst = Tqkv + 1024 * 576; Ksrc = 512; Kdst = 576; }
  else if (w == 3) { src = Wf1; dst = Tf1;               Ksrc = 512; Kdst = 512; }
  else             { src = Wf2; dst = Tf2;               Ksrc = 512; Kdst = 512; }
  int kb = blockIdx.x * 64;
  if (kb >= Kdst) return;
  int nb = blockIdx.y * 64;
  int tid = threadIdx.x;
  #pragma unroll
  for (int i = 0; i < 16; ++i) {
    int idx = tid + i * 256;
    int r = idx >> 6, c = idx & 63;
    tile[r][c] = (kb + r < Ksrc) ? src[(size_t)(kb + r) * DMODEL + nb + c] : 0.0f;
  }
  __syncthreads();
  #pragma unroll
  for (int i = 0; i < 16; ++i) {
    int idx = tid + i * 256;
    int r = idx >> 6, c = idx & 63;
    dst[(size_t)(nb + r) * Kdst + kb + c] = f2bf(tile[c][r]);
  }
}

__global__ void lnx_kernel(const float* __restrict__ x, const float* __restrict__ g,
                           const float* __restrict__ b, float* __restrict__ xt,
                           u16* __restrict__ qkin) {
  int row = blockIdx.x * 4 + (threadIdx.x >> 6);
  int lane = threadIdx.x & 63;
  const float* xr = x + (size_t)row * DMODEL + lane * 8;
  float v[8];
  float4 a0 = *(const float4*)xr;
  float4 a1 = *(const float4*)(xr + 4);
  v[0]=a0.x; v[1]=a0.y; v[2]=a0.z; v[3]=a0.w; v[4]=a1.x; v[5]=a1.y; v[6]=a1.z; v[7]=a1.w;
  float s = 0.f, ss = 0.f;
  #pragma unroll
  for (int j = 0; j < 8; ++j) { s += v[j]; ss += v[j]*v[j]; }
  #pragma unroll
  for (int off = 32; off > 0; off >>= 1) { s += __shfl_xor(s, off); ss += __shfl_xor(ss, off); }
  float mu = s * (1.0f / DMODEL);
  float var = ss * (1.0f / DMODEL) - mu * mu;
  float rs = rsqrtf(var + 1e-5f);
  float4 g0 = *(const float4*)(g + lane * 8);
  float4 g1v = *(const float4*)(g + lane * 8 + 4);
  float4 b0 = *(const float4*)(b + lane * 8);
  float4 b1v = *(const float4*)(b + lane * 8 + 4);
  float gg[8] = {g0.x,g0.y,g0.z,g0.w,g1v.x,g1v.y,g1v.z,g1v.w};
  float bb[8] = {b0.x,b0.y,b0.z,b0.w,b1v.x,b1v.y,b1v.z,b1v.w};
  float o[8]; u16x8 ob;
  #pragma unroll
  for (int j = 0; j < 8; ++j) { o[j] = (v[j]-mu)*rs*gg[j] + bb[j]; ob[j] = f2bf(o[j]); }
  float* xo = xt + (size_t)row * DMODEL + lane * 8;
  *(float4*)xo = make_float4(o[0],o[1],o[2],o[3]);
  *(float4*)(xo + 4) = make_float4(o[4],o[5],o[6],o[7]);
  *(u16x8*)(qkin + (size_t)row * DCAT + lane * 8) = ob;
}

__global__ void lne_kernel(const float* __restrict__ e, const float* __restrict__ g,
                           const float* __restrict__ b, u16* __restrict__ qkin) {
  int row = blockIdx.x * 4 + (threadIdx.x >> 6);
  int lane = threadIdx.x & 63;
  float v = e[(size_t)row * DEMB + lane];
  float s = v, ss = v * v;
  #pragma unroll
  for (int off = 32; off > 0; off >>= 1) { s += __shfl_xor(s, off); ss += __shfl_xor(ss, off); }
  float mu = s * (1.0f / DEMB);
  float var = ss * (1.0f / DEMB) - mu * mu;
  float rs = rsqrtf(var + 1e-5f);
  float o = (v - mu) * rs * g[lane] + b[lane];
  qkin[(size_t)row * DCAT + DMODEL + lane] = f2bf(o);
}

__global__ void ln3_kernel(const float* __restrict__ xt, const float* __restrict__ g,
                           const float* __restrict__ b, u16* __restrict__ hb) {
  int row = blockIdx.x * 4 + (threadIdx.x >> 6);
  int lane = threadIdx.x & 63;
  const float* xr = xt + (size_t)row * DMODEL + lane * 8;
  float v[8];
  float4 a0 = *(const float4*)xr;
  float4 a1 = *(const float4*)(xr + 4);
  v[0]=a0.x; v[1]=a0.y; v[2]=a0.z; v[3]=a0.w; v[4]=a1.x; v[5]=a1.y; v[6]=a1.z; v[7]=a1.w;
  float s = 0.f, ss = 0.f;
  #pragma unroll
  for (int j = 0; j < 8; ++j) { s += v[j]; ss += v[j]*v[j]; }
  #pragma unroll
  for (int off = 32; off > 0; off >>= 1) { s += __shfl_xor(s, off); ss += __shfl_xor(ss, off); }
  float mu = s * (1.0f / DMODEL);
  float var = ss * (1.0f / DMODEL) - mu * mu;
  float rs = rsqrtf(var + 1e-5f);
  float4 g0 = *(const float4*)(g + lane * 8);
  float4 g1v = *(const float4*)(g + lane * 8 + 4);
  float4 b0 = *(const float4*)(b + lane * 8);
  float4 b1v = *(const float4*)(b + lane * 8 + 4);
  float gg[8] = {g0.x,g0.y,g0.z,g0.w,g1v.x,g1v.y,g1v.z,g1v.w};
  float bb[8] = {b0.x,b0.y,b0.z,b0.w,b1v.x,b1v.y,b1v.z,b1v.w};
  u16x8 ob;
  #pragma unroll
  for (int j = 0; j < 8; ++j) ob[j] = f2bf((v[j]-mu)*rs*gg[j] + bb[j]);
  *(u16x8*)(hb + (size_t)row * DMODEL + lane * 8) = ob;
}

// BM=64, BN=64, BK=64, 4 waves (2x2). MODE 0: fused QKV (outb = qhd base;
// khd at +NTOK*DMODEL, vT at +2*NTOK*DMODEL). MODE 3: FFN1. MODE 4: FFN2.
template<int MODE>
__global__ __launch_bounds__(256) void gemm_kernel(
    const u16* __restrict__ A, int lda, const u16* __restrict__ Bt, int K,
    u16* __restrict__ outb, float* __restrict__ outf,
    const float* __restrict__ bias, const float* __restrict__ xt) {
  __shared__ __align__(16) u16 smem[8192];
  u16* Al = smem;
  u16* Bl = smem + 4096;
  int tid = threadIdx.x, lane = tid & 63, wid = tid >> 6;
  int li = lane & 15, g4 = lane >> 4;
  int n0 = blockIdx.x * 64, m0 = blockIdx.y * 64;
  int wr = (wid >> 1) * 32, wc = (wid & 1) * 32;
  f32x4 acc[2][2] = {};
  for (int k0 = 0; k0 < K; k0 += 64) {
    #pragma unroll
    for (int i = 0; i < 2; ++i) {
      int idx = i * 256 + tid;
      int row = idx >> 3, cb = (idx & 7) * 8;
      gload16(A + (size_t)(m0 + row) * lda + k0 + cb, (char*)Al + idx * 16);
    }
    #pragma unroll
    for (int i = 0; i < 2; ++i) {
      int idx = i * 256 + tid;
      int row = idx >> 3, cb = (idx & 7) * 8;
      gload16(Bt + (size_t)(n0 + row) * K + k0 + cb, (char*)Bl + idx * 16);
    }
    __syncthreads();
    #pragma unroll
    for (int kk = 0; kk < 2; ++kk) {
      s16x8 af[2], bfv[2];
      #pragma unroll
      for (int mi = 0; mi < 2; ++mi)
        af[mi] = *(const s16x8*)&Al[(wr + mi * 16 + li) * 64 + kk * 32 + g4 * 8];
      #pragma unroll
      for (int ni = 0; ni < 2; ++ni)
        bfv[ni] = *(const s16x8*)&Bl[(wc + ni * 16 + li) * 64 + kk * 32 + g4 * 8];
      #pragma unroll
      for (int mi = 0; mi < 2; ++mi)
        #pragma unroll
        for (int ni = 0; ni < 2; ++ni)
          acc[mi][ni] = __builtin_amdgcn_mfma_f32_16x16x32_bf16(af[mi], bfv[ni], acc[mi][ni], 0, 0, 0);
    }
    __syncthreads();
  }
  if (MODE == 0) {
    if (n0 < 1024) {
      float scale = (n0 < 512) ? QSCALE : 1.0f;
      int nb = (n0 < 512) ? n0 : n0 - 512;
      u16* dst = outb + ((n0 < 512) ? 0 : (size_t)NTOK * DMODEL);
      #pragma unroll
      for (int mi = 0; mi < 2; ++mi)
        #pragma unroll
        for (int ni = 0; ni < 2; ++ni) {
          int col = nb + wc + ni * 16 + li;
          int h = col >> 6, dh = col & 63;
          #pragma unroll
          for (int r = 0; r < 4; ++r) {
            int row = m0 + wr + mi * 16 + g4 * 4 + r;
            dst[((size_t)h * NTOK + row) * DHEAD + dh] = f2bf(acc[mi][ni][r] * scale);
          }
        }
    } else {
      u16* vT = outb + (size_t)2 * NTOK * DMODEL;
      u16* tp = smem;  // [64][80]
      __syncthreads();
      #pragma unroll
      for (int mi = 0; mi < 2; ++mi)
        #pragma unroll
        for (int ni = 0; ni < 2; ++ni) {
          int cl = wc + ni * 16 + li;
          int r0 = wr + mi * 16 + g4 * 4;
          u16x4 pk;
          pk[0] = f2bf(acc[mi][ni][0]); pk[1] = f2bf(acc[mi][ni][1]);
          pk[2] = f2bf(acc[mi][ni][2]); pk[3] = f2bf(acc[mi][ni][3]);
          *(u16x4*)&tp[cl * 80 + r0] = pk;
        }
      __syncthreads();
      for (int c = tid; c < 512; c += 256) {
        int cl = c >> 3, seg = c & 7;
        u16x8 v = *(const u16x8*)&tp[cl * 80 + seg * 8];
        *(u16x8*)&vT[(size_t)(n0 - 1024 + cl) * NTOK + m0 + seg * 8] = v;
      }
    }
  } else {
    #pragma unroll
    for (int mi = 0; mi < 2; ++mi)
      #pragma unroll
      for (int ni = 0; ni < 2; ++ni) {
        int col = n0 + wc + ni * 16 + li;
        float bv = bias[col];
        #pragma unroll
        for (int r = 0; r < 4; ++r) {
          int row = m0 + wr + mi * 16 + g4 * 4 + r;
          float v = acc[mi][ni][r] + bv;
          if (MODE == 3) {
            v = fmaxf(v, 0.0f);
            outb[(size_t)row * DMODEL + col] = f2bf(v);
          } else {
            outf[(size_t)row * DMODEL + col] = v + xt[(size_t)row * DMODEL + col];
          }
        }
      }
  }
}

// fused flash attention v4 (fixed-max softmax: P = exp2(score), Q pre-scaled).
// grid 1024: head = bid&7 (XCD/L2 locality), qtile = bid>>3 (32 q rows).
// 4 waves = 4 key-splits of 1024 keys each. 256 threads.
// __launch_bounds__(256,2): this compiler caps VGPR at 256/w -> w=2 gives 128,
// which fits the ~110-reg live state with NO spills (w=4 -> 64 regs spilled).
__global__ __launch_bounds__(256, 2) void attn_kernel(
    const u16* __restrict__ qh, const u16* __restrict__ kh,
    const u16* __restrict__ vT, float* __restrict__ xt) {
  __shared__ __align__(16) u16 p_lds[4][2048];   // per wave [32 q][64 k] bf16 (XOR-swizzled)
  __shared__ float o_buf[2][32][66];             // stride 66: scalar stores max 2/bank
  __shared__ float l_lds[4][32];
  int tid = threadIdx.x, lane = tid & 63, wk = tid >> 6;
  int li = lane & 15, g4 = lane >> 4;
  int h = blockIdx.x & 7, qt = blockIdx.x >> 3;
  int q0 = qt * 32;
  const u16* qbase = qh + ((size_t)h * NTOK + q0) * DHEAD;
  s16x8 bq[2][2];
  #pragma unroll
  for (int mi = 0; mi < 2; ++mi)
    #pragma unroll
    for (int kk = 0; kk < 2; ++kk)
      bq[mi][kk] = *(const s16x8*)(qbase + (mi * 16 + li) * DHEAD + kk * 32 + g4 * 8);
  f32x4 o[2][4] = {};
  float l_run[2] = {0.f, 0.f};
  char* pw = (char*)&p_lds[wk][0];
  const u16* kh_h = kh + (size_t)h * NTOK * DHEAD;
  const u16* v_h = vT + (size_t)(h * DHEAD) * NTOK;
  for (int t = 0; t < 16; ++t) {
    int kb = wk * 1024 + t * 64;
    const u16* kbase = kh_h + (size_t)kb * DHEAD;
    s16x8 ak[4][2];
    #pragma unroll
    for (int ni = 0; ni < 4; ++ni)
      #pragma unroll
      for (int kk = 0; kk < 2; ++kk)
        ak[ni][kk] = *(const s16x8*)(kbase + (ni * 16 + li) * DHEAD + kk * 32 + g4 * 8);
    #pragma unroll
    for (int mi = 0; mi < 2; ++mi) {
      f32x4 st[4];
      #pragma unroll
      for (int ni = 0; ni < 4; ++ni) {
        f32x4 z = {0.f, 0.f, 0.f, 0.f};
        z = __builtin_amdgcn_mfma_f32_16x16x32_bf16(ak[ni][0], bq[mi][0], z, 0, 0, 0);
        st[ni] = __builtin_amdgcn_mfma_f32_16x16x32_bf16(ak[ni][1], bq[mi][1], z, 0, 0, 0);
      }
      int rowoff = (mi * 16 + li) * 128;
      int swz = (li & 7) << 4;
      float rs = 0.f;
      #pragma unroll
      for (int ni = 0; ni < 4; ++ni) {
        float p0 = __builtin_amdgcn_exp2f(st[ni][0]);
        float p1 = __builtin_amdgcn_exp2f(st[ni][1]);
        float p2 = __builtin_amdgcn_exp2f(st[ni][2]);
        float p3 = __builtin_amdgcn_exp2f(st[ni][3]);
        rs += (p0 + p1) + (p2 + p3);
        uint2 pk;
        pk.x = cvtpk_bf16(p0, p1);
        pk.y = cvtpk_bf16(p2, p3);
        *(uint2*)(pw + rowoff + (((ni * 16 + g4 * 4) * 2) ^ swz)) = pk;
      }
      l_run[mi] += rs;
    }
    #pragma unroll
    for (int ki = 0; ki < 2; ++ki) {
      s16x8 ap[2], bv[4];
      #pragma unroll
      for (int mi = 0; mi < 2; ++mi)
        ap[mi] = *(const s16x8*)(pw + (mi * 16 + li) * 128 +
                                 (((ki * 32 + g4 * 8) * 2) ^ ((li & 7) << 4)));
      #pragma unroll
      for (int di = 0; di < 4; ++di)
        bv[di] = *(const s16x8*)(v_h + (size_t)(di * 16 + li) * NTOK + kb + ki * 32 + g4 * 8);
      #pragma unroll
      for (int mi = 0; mi < 2; ++mi)
        #pragma unroll
        for (int di = 0; di < 4; ++di)
          o[mi][di] = __builtin_amdgcn_mfma_f32_16x16x32_bf16(ap[mi], bv[di], o[mi][di], 0, 0, 0);
    }
  }
  #pragma unroll
  for (int mi = 0; mi < 2; ++mi) {
    float v = l_run[mi];
    v += __shfl_xor(v, 16);
    v += __shfl_xor(v, 32);
    if (g4 == 0) l_lds[wk][mi * 16 + li] = v;
  }
  __syncthreads();
  if (wk < 2) {
    #pragma unroll
    for (int mi = 0; mi < 2; ++mi)
      #pragma unroll
      for (int di = 0; di < 4; ++di)
        #pragma unroll
        for (int r = 0; r < 4; ++r)
          o_buf[wk][mi * 16 + g4 * 4 + r][di * 16 + li] = o[mi][di][r];
  }
  __syncthreads();
  if (wk >= 2) {
    #pragma unroll
    for (int mi = 0; mi < 2; ++mi)
      #pragma unroll
      for (int di = 0; di < 4; ++di)
        #pragma unroll
        for (int r = 0; r < 4; ++r)
          o_buf[wk - 2][mi * 16 + g4 * 4 + r][di * 16 + li] += o[mi][di][r];
  }
  __syncthreads();
  int row = tid >> 3;
  int c8 = (tid & 7) * 8;
  float lt = l_lds[0][row] + l_lds[1][row] + l_lds[2][row] + l_lds[3][row];
  float rcp = 1.0f / lt;
  float* dst = xt + (size_t)(q0 + row) * DMODEL + h * DHEAD + c8;
  #pragma unroll
  for (int j = 0; j < 8; ++j)
    dst[j] += (o_buf[0][row][c8 + j] + o_buf[1][row][c8 + j]) * rcp;
}

extern "C" void kernel_launch(void* const* d_in, const int* in_sizes, int n_in,
                              void* d_out, int out_size, void* d_ws, size_t ws_size,
                              hipStream_t stream) {
  const float* x   = (const float*)d_in[0];
  const float* emb = (const float*)d_in[1];
  const float* Wq  = (const float*)d_in[2];
  const float* Wk  = (const float*)d_in[3];
  const float* Wv  = (const float*)d_in[4];
  const float* g1  = (const float*)d_in[5];
  const float* b1  = (const float*)d_in[6];
  const float* g2  = (const float*)d_in[7];
  const float* b2  = (const float*)d_in[8];
  const float* g3  = (const float*)d_in[9];
  const float* b3  = (const float*)d_in[10];
  const float* Wf1 = (const float*)d_in[11];
  const float* bf1 = (const float*)d_in[12];
  const float* Wf2 = (const float*)d_in[13];
  const float* bf2 = (const float*)d_in[14];
  float* out = (float*)d_out;

  char* ws = (char*)d_ws;
  size_t off = 0;
  auto alloc = [&](size_t bytes) { void* p = ws + off; off += (bytes + 255) & ~255ull; return p; };
  float* xt = (float*)alloc((size_t)NTOK * DMODEL * 4);
  u16* qkin = (u16*)alloc((size_t)NTOK * DCAT * 2);
  u16* hb   = (u16*)alloc((size_t)NTOK * DMODEL * 2);
  u16* r1   = (u16*)alloc((size_t)NTOK * DMODEL * 2);
  u16* qkvh = (u16*)alloc((size_t)3 * NTOK * DMODEL * 2);  // qhd | khd | vT contiguous
  u16* Tqkv = (u16*)alloc((size_t)1536 * DCAT * 2);
  u16* Tf1  = (u16*)alloc((size_t)DMODEL * DMODEL * 2);
  u16* Tf2  = (u16*)alloc((size_t)DMODEL * DMODEL * 2);
  u16* qhd = qkvh;
  u16* khd = qkvh + (size_t)NTOK * DMODEL;
  u16* vTd = qkvh + (size_t)2 * NTOK * DMODEL;

  wtrans_kernel<<<dim3(9, 8, 5), 256, 0, stream>>>(Wq, Wk, Wv, Wf1, Wf2, Tqkv, Tf1, Tf2);
  lnx_kernel<<<1024, 256, 0, stream>>>(x, g1, b1, xt, qkin);
  lne_kernel<<<1024, 256, 0, stream>>>(emb, g2, b2, qkin);
  gemm_kernel<0><<<dim3(24, 64), 256, 0, stream>>>(qkin, DCAT, Tqkv, DCAT, qkvh, nullptr, nullptr, nullptr);
  attn_kernel<<<1024, 256, 0, stream>>>(qhd, khd, vTd, xt);
  ln3_kernel<<<1024, 256, 0, stream>>>(xt, g3, b3, hb);
  gemm_kernel<3><<<dim3(8, 64), 256, 0, stream>>>(hb, DMODEL, Tf1, DMODEL, r1, nullptr, bf1, nullptr);
  gemm_kernel<4><<<dim3(8, 64), 256, 0, stream>>>(r1, DMODEL, Tf2, DMODEL, nullptr, out, bf2, xt);
}

// Round 6
// 112.964 us; speedup vs baseline: 1.6097x; 1.5851x over previous
//
#include <hip/hip_runtime.h>

#define NTOK 4096
#define DMODEL 512
#define DEMB 64
#define DCAT 576
#define NHEAD 8
#define DHEAD 64
#define QSCALE 0.18033688011112042f  // (1/8) * log2(e)

typedef float f32x4 __attribute__((ext_vector_type(4)));
typedef short s16x8 __attribute__((ext_vector_type(8)));
typedef unsigned short u16;
typedef u16 u16x4 __attribute__((ext_vector_type(4)));
typedef u16 u16x8 __attribute__((ext_vector_type(8)));
typedef unsigned int u32;

__device__ __forceinline__ u16 f2bf(float f) {
  union { float f; unsigned u; } v; v.f = f;
  unsigned r = v.u + 0x7fffu + ((v.u >> 16) & 1u);
  return (u16)(r >> 16);
}

__device__ __forceinline__ float bf2f(u16 u) {
  union { unsigned u; float f; } v; v.u = ((unsigned)u) << 16;
  return v.f;
}

__device__ __forceinline__ u32 cvtpk_bf16(float lo, float hi) {
  u32 r;
  asm("v_cvt_pk_bf16_f32 %0, %1, %2" : "=v"(r) : "v"(lo), "v"(hi));
  return r;
}

__device__ __forceinline__ void gload16(const void* g, void* lds) {
  __builtin_amdgcn_global_load_lds((const __attribute__((address_space(1))) u32*)g,
                                   (__attribute__((address_space(3))) u32*)lds, 16, 0, 0);
}

__global__ void wtrans_kernel(const float* __restrict__ Wq, const float* __restrict__ Wk,
                              const float* __restrict__ Wv, const float* __restrict__ Wf1,
                              const float* __restrict__ Wf2,
                              u16* __restrict__ Tqkv, u16* __restrict__ Tf1, u16* __restrict__ Tf2) {
  __shared__ float tile[64][65];
  int w = blockIdx.z;
  const float* src; u16* dst; int Ksrc, Kdst;
  if (w == 0)      { src = Wq;  dst = Tqkv;              Ksrc = 576; Kdst = 576; }
  else if (w == 1) { src = Wk;  dst = Tqkv + 512 * 576;  Ksrc = 576; Kdst = 576; }
  else if (w == 2) { src = Wv;  dst = Tqkv + 1024 * 576; Ksrc = 512; Kdst = 576; }
  else if (w == 3) { src = Wf1; dst = Tf1;               Ksrc = 512; Kdst = 512; }
  else             { src = Wf2; dst = Tf2;               Ksrc = 512; Kdst = 512; }
  int kb = blockIdx.x * 64;
  if (kb >= Kdst) return;
  int nb = blockIdx.y * 64;
  int tid = threadIdx.x;
  #pragma unroll
  for (int i = 0; i < 16; ++i) {
    int idx = tid + i * 256;
    int r = idx >> 6, c = idx & 63;
    tile[r][c] = (kb + r < Ksrc) ? src[(size_t)(kb + r) * DMODEL + nb + c] : 0.0f;
  }
  __syncthreads();
  #pragma unroll
  for (int i = 0; i < 16; ++i) {
    int idx = tid + i * 256;
    int r = idx >> 6, c = idx & 63;
    dst[(size_t)(nb + r) * Kdst + kb + c] = f2bf(tile[c][r]);
  }
}

__global__ void lnx_kernel(const float* __restrict__ x, const float* __restrict__ g,
                           const float* __restrict__ b, float* __restrict__ xt,
                           u16* __restrict__ qkin) {
  int row = blockIdx.x * 4 + (threadIdx.x >> 6);
  int lane = threadIdx.x & 63;
  const float* xr = x + (size_t)row * DMODEL + lane * 8;
  float v[8];
  float4 a0 = *(const float4*)xr;
  float4 a1 = *(const float4*)(xr + 4);
  v[0]=a0.x; v[1]=a0.y; v[2]=a0.z; v[3]=a0.w; v[4]=a1.x; v[5]=a1.y; v[6]=a1.z; v[7]=a1.w;
  float s = 0.f, ss = 0.f;
  #pragma unroll
  for (int j = 0; j < 8; ++j) { s += v[j]; ss += v[j]*v[j]; }
  #pragma unroll
  for (int off = 32; off > 0; off >>= 1) { s += __shfl_xor(s, off); ss += __shfl_xor(ss, off); }
  float mu = s * (1.0f / DMODEL);
  float var = ss * (1.0f / DMODEL) - mu * mu;
  float rs = rsqrtf(var + 1e-5f);
  float4 g0 = *(const float4*)(g + lane * 8);
  float4 g1v = *(const float4*)(g + lane * 8 + 4);
  float4 b0 = *(const float4*)(b + lane * 8);
  float4 b1v = *(const float4*)(b + lane * 8 + 4);
  float gg[8] = {g0.x,g0.y,g0.z,g0.w,g1v.x,g1v.y,g1v.z,g1v.w};
  float bb[8] = {b0.x,b0.y,b0.z,b0.w,b1v.x,b1v.y,b1v.z,b1v.w};
  float o[8]; u16x8 ob;
  #pragma unroll
  for (int j = 0; j < 8; ++j) { o[j] = (v[j]-mu)*rs*gg[j] + bb[j]; ob[j] = f2bf(o[j]); }
  float* xo = xt + (size_t)row * DMODEL + lane * 8;
  *(float4*)xo = make_float4(o[0],o[1],o[2],o[3]);
  *(float4*)(xo + 4) = make_float4(o[4],o[5],o[6],o[7]);
  *(u16x8*)(qkin + (size_t)row * DCAT + lane * 8) = ob;
}

__global__ void lne_kernel(const float* __restrict__ e, const float* __restrict__ g,
                           const float* __restrict__ b, u16* __restrict__ qkin) {
  int row = blockIdx.x * 4 + (threadIdx.x >> 6);
  int lane = threadIdx.x & 63;
  float v = e[(size_t)row * DEMB + lane];
  float s = v, ss = v * v;
  #pragma unroll
  for (int off = 32; off > 0; off >>= 1) { s += __shfl_xor(s, off); ss += __shfl_xor(ss, off); }
  float mu = s * (1.0f / DEMB);
  float var = ss * (1.0f / DEMB) - mu * mu;
  float rs = rsqrtf(var + 1e-5f);
  float o = (v - mu) * rs * g[lane] + b[lane];
  qkin[(size_t)row * DCAT + DMODEL + lane] = f2bf(o);
}

// ln3 v2: merges attention partials (obuf bf16 slices + lbuf), updates xt in
// place (xt += O/l) and writes hb = LN(xt_new) as bf16.
__global__ void ln3_kernel(float* __restrict__ xt, const float* __restrict__ g,
                           const float* __restrict__ b, u16* __restrict__ hb,
                           const u16* __restrict__ obuf, const float* __restrict__ lbuf) {
  int row = blockIdx.x * 4 + (threadIdx.x >> 6);
  int lane = threadIdx.x & 63;
  int h = lane >> 3;
  int dh0 = (lane & 7) * 8;
  float* xr = xt + (size_t)row * DMODEL + lane * 8;
  float v[8];
  float4 a0 = *(const float4*)xr;
  float4 a1 = *(const float4*)(xr + 4);
  v[0]=a0.x; v[1]=a0.y; v[2]=a0.z; v[3]=a0.w; v[4]=a1.x; v[5]=a1.y; v[6]=a1.z; v[7]=a1.w;
  float osum[8] = {};
  float lsum = 0.f;
  #pragma unroll
  for (int s = 0; s < 4; ++s) {
    size_t hb_idx = (size_t)(s * 8 + h) * NTOK + row;
    u16x8 ov = *(const u16x8*)(obuf + hb_idx * 64 + dh0);
    lsum += lbuf[hb_idx];
    #pragma unroll
    for (int j = 0; j < 8; ++j) osum[j] += bf2f(ov[j]);
  }
  float rcpl = 1.0f / lsum;
  #pragma unroll
  for (int j = 0; j < 8; ++j) v[j] += osum[j] * rcpl;
  // write updated xt (residual base for FFN2)
  *(float4*)xr = make_float4(v[0],v[1],v[2],v[3]);
  *(float4*)(xr + 4) = make_float4(v[4],v[5],v[6],v[7]);
  float s = 0.f, ss = 0.f;
  #pragma unroll
  for (int j = 0; j < 8; ++j) { s += v[j]; ss += v[j]*v[j]; }
  #pragma unroll
  for (int off = 32; off > 0; off >>= 1) { s += __shfl_xor(s, off); ss += __shfl_xor(ss, off); }
  float mu = s * (1.0f / DMODEL);
  float var = ss * (1.0f / DMODEL) - mu * mu;
  float rs = rsqrtf(var + 1e-5f);
  float4 g0 = *(const float4*)(g + lane * 8);
  float4 g1v = *(const float4*)(g + lane * 8 + 4);
  float4 b0 = *(const float4*)(b + lane * 8);
  float4 b1v = *(const float4*)(b + lane * 8 + 4);
  float gg[8] = {g0.x,g0.y,g0.z,g0.w,g1v.x,g1v.y,g1v.z,g1v.w};
  float bb[8] = {b0.x,b0.y,b0.z,b0.w,b1v.x,b1v.y,b1v.z,b1v.w};
  u16x8 ob;
  #pragma unroll
  for (int j = 0; j < 8; ++j) ob[j] = f2bf((v[j]-mu)*rs*gg[j] + bb[j]);
  *(u16x8*)(hb + (size_t)row * DMODEL + lane * 8) = ob;
}

// BM=64, BN=64, BK=64, 4 waves (2x2). MODE 0: fused QKV (outb = qhd base;
// khd at +NTOK*DMODEL, vT at +2*NTOK*DMODEL). MODE 3: FFN1. MODE 4: FFN2.
template<int MODE>
__global__ __launch_bounds__(256) void gemm_kernel(
    const u16* __restrict__ A, int lda, const u16* __restrict__ Bt, int K,
    u16* __restrict__ outb, float* __restrict__ outf,
    const float* __restrict__ bias, const float* __restrict__ xt) {
  __shared__ __align__(16) u16 smem[8192];
  u16* Al = smem;
  u16* Bl = smem + 4096;
  int tid = threadIdx.x, lane = tid & 63, wid = tid >> 6;
  int li = lane & 15, g4 = lane >> 4;
  int n0 = blockIdx.x * 64, m0 = blockIdx.y * 64;
  int wr = (wid >> 1) * 32, wc = (wid & 1) * 32;
  f32x4 acc[2][2] = {};
  for (int k0 = 0; k0 < K; k0 += 64) {
    #pragma unroll
    for (int i = 0; i < 2; ++i) {
      int idx = i * 256 + tid;
      int row = idx >> 3, cb = (idx & 7) * 8;
      gload16(A + (size_t)(m0 + row) * lda + k0 + cb, (char*)Al + idx * 16);
    }
    #pragma unroll
    for (int i = 0; i < 2; ++i) {
      int idx = i * 256 + tid;
      int row = idx >> 3, cb = (idx & 7) * 8;
      gload16(Bt + (size_t)(n0 + row) * K + k0 + cb, (char*)Bl + idx * 16);
    }
    __syncthreads();
    #pragma unroll
    for (int kk = 0; kk < 2; ++kk) {
      s16x8 af[2], bfv[2];
      #pragma unroll
      for (int mi = 0; mi < 2; ++mi)
        af[mi] = *(const s16x8*)&Al[(wr + mi * 16 + li) * 64 + kk * 32 + g4 * 8];
      #pragma unroll
      for (int ni = 0; ni < 2; ++ni)
        bfv[ni] = *(const s16x8*)&Bl[(wc + ni * 16 + li) * 64 + kk * 32 + g4 * 8];
      #pragma unroll
      for (int mi = 0; mi < 2; ++mi)
        #pragma unroll
        for (int ni = 0; ni < 2; ++ni)
          acc[mi][ni] = __builtin_amdgcn_mfma_f32_16x16x32_bf16(af[mi], bfv[ni], acc[mi][ni], 0, 0, 0);
    }
    __syncthreads();
  }
  if (MODE == 0) {
    if (n0 < 1024) {
      float scale = (n0 < 512) ? QSCALE : 1.0f;
      int nb = (n0 < 512) ? n0 : n0 - 512;
      u16* dst = outb + ((n0 < 512) ? 0 : (size_t)NTOK * DMODEL);
      #pragma unroll
      for (int mi = 0; mi < 2; ++mi)
        #pragma unroll
        for (int ni = 0; ni < 2; ++ni) {
          int col = nb + wc + ni * 16 + li;
          int h = col >> 6, dh = col & 63;
          #pragma unroll
          for (int r = 0; r < 4; ++r) {
            int row = m0 + wr + mi * 16 + g4 * 4 + r;
            dst[((size_t)h * NTOK + row) * DHEAD + dh] = f2bf(acc[mi][ni][r] * scale);
          }
        }
    } else {
      u16* vT = outb + (size_t)2 * NTOK * DMODEL;
      u16* tp = smem;  // [64][80]
      __syncthreads();
      #pragma unroll
      for (int mi = 0; mi < 2; ++mi)
        #pragma unroll
        for (int ni = 0; ni < 2; ++ni) {
          int cl = wc + ni * 16 + li;
          int r0 = wr + mi * 16 + g4 * 4;
          u16x4 pk;
          pk[0] = f2bf(acc[mi][ni][0]); pk[1] = f2bf(acc[mi][ni][1]);
          pk[2] = f2bf(acc[mi][ni][2]); pk[3] = f2bf(acc[mi][ni][3]);
          *(u16x4*)&tp[cl * 80 + r0] = pk;
        }
      __syncthreads();
      for (int c = tid; c < 512; c += 256) {
        int cl = c >> 3, seg = c & 7;
        u16x8 v = *(const u16x8*)&tp[cl * 80 + seg * 8];
        *(u16x8*)&vT[(size_t)(n0 - 1024 + cl) * NTOK + m0 + seg * 8] = v;
      }
    }
  } else {
    #pragma unroll
    for (int mi = 0; mi < 2; ++mi)
      #pragma unroll
      for (int ni = 0; ni < 2; ++ni) {
        int col = n0 + wc + ni * 16 + li;
        float bv = bias[col];
        #pragma unroll
        for (int r = 0; r < 4; ++r) {
          int row = m0 + wr + mi * 16 + g4 * 4 + r;
          float v = acc[mi][ni][r] + bv;
          if (MODE == 3) {
            v = fmaxf(v, 0.0f);
            outb[(size_t)row * DMODEL + col] = f2bf(v);
          } else {
            outf[(size_t)row * DMODEL + col] = v + xt[(size_t)row * DMODEL + col];
          }
        }
      }
  }
}

// fused flash attention v5: fixed-max softmax (P = exp2, Q pre-scaled),
// LDS-staged K/V shared by 4 q-waves, double-buffered (T3 min-2-phase).
// grid 1024: h = bid&7 (XCD/L2), ks = (bid>>3)&3 (key quarter), qt = bid>>5.
// Block: 4 waves x 32 q = 128 q rows, iterating 16 tiles of 64 keys.
// Writes UNNORMALIZED partial O (bf16) + partial l per key-quarter slice;
// ln3 merges. LDS: K/V dbuf 32KB + P 16KB = 48KB -> 3 blocks/CU.
__global__ __launch_bounds__(256) void attn_kernel(
    const u16* __restrict__ qh, const u16* __restrict__ kh,
    const u16* __restrict__ vT, u16* __restrict__ obuf, float* __restrict__ lbuf) {
  __shared__ __align__(16) u16 kbuf[2][4096];   // [64 keys][64 dh], 16B-chunk XOR-swizzled
  __shared__ __align__(16) u16 vbuf[2][4096];   // [64 dh][64 keys], same swizzle
  __shared__ __align__(16) u16 p_lds[4][2048];  // per wave [32 q][64 k]
  int tid = threadIdx.x, lane = tid & 63, w = tid >> 6;
  int li = lane & 15, g4 = lane >> 4;
  int li7 = li & 7;
  int h = blockIdx.x & 7, ks = (blockIdx.x >> 3) & 3, qt = blockIdx.x >> 5;
  int q0w = qt * 128 + w * 32;
  int ko0 = ks * 1024;
  const u16* qbase = qh + ((size_t)h * NTOK + q0w) * DHEAD;
  s16x8 bq[2][2];
  #pragma unroll
  for (int mi = 0; mi < 2; ++mi)
    #pragma unroll
    for (int kk = 0; kk < 2; ++kk)
      bq[mi][kk] = *(const s16x8*)(qbase + (mi * 16 + li) * DHEAD + kk * 32 + g4 * 8);
  f32x4 o[2][4] = {};
  float l_run[2] = {0.f, 0.f};
  char* pw = (char*)&p_lds[w][0];
  const char* kh_b = (const char*)(kh + (size_t)h * NTOK * DHEAD);
  const char* v_b = (const char*)(vT + (size_t)h * DHEAD * NTOK);

  // stage key-tile at global key offset ko into buffer c (this wave's share)
  auto stage = [&](int c, int ko) {
    #pragma unroll
    for (int i = 0; i < 2; ++i) {
      int s = w * 128 + i * 64 + lane;
      int row = s >> 3;
      int cg = (s & 7) ^ (row & 7);
      gload16(kh_b + (size_t)(ko + row) * 128 + cg * 16,
              (char*)&kbuf[c][0] + (w * 128 + i * 64) * 16);
      gload16(v_b + (size_t)row * (NTOK * 2) + (size_t)ko * 2 + cg * 16,
              (char*)&vbuf[c][0] + (w * 128 + i * 64) * 16);
    }
  };

  stage(0, ko0);
  asm volatile("s_waitcnt vmcnt(0)" ::: "memory");
  __builtin_amdgcn_sched_barrier(0);
  __syncthreads();

  for (int t = 0; t < 16; ++t) {
    int cur = t & 1;
    if (t < 15) stage(cur ^ 1, ko0 + (t + 1) * 64);
    const u16* Kl = &kbuf[cur][0];
    const u16* Vl = &vbuf[cur][0];
    s16x8 ak[4][2];
    #pragma unroll
    for (int ni = 0; ni < 4; ++ni)
      #pragma unroll
      for (int kk = 0; kk < 2; ++kk)
        ak[ni][kk] = *(const s16x8*)&Kl[(ni * 16 + li) * 64 +
                                        (((kk * 64 + g4 * 16) ^ (li7 << 4)) >> 1)];
    #pragma unroll
    for (int mi = 0; mi < 2; ++mi) {
      f32x4 st[4];
      #pragma unroll
      for (int ni = 0; ni < 4; ++ni) {
        f32x4 z = {0.f, 0.f, 0.f, 0.f};
        z = __builtin_amdgcn_mfma_f32_16x16x32_bf16(ak[ni][0], bq[mi][0], z, 0, 0, 0);
        st[ni] = __builtin_amdgcn_mfma_f32_16x16x32_bf16(ak[ni][1], bq[mi][1], z, 0, 0, 0);
      }
      int rowoff = (mi * 16 + li) * 128;
      int swz = li7 << 4;
      float rs = 0.f;
      #pragma unroll
      for (int ni = 0; ni < 4; ++ni) {
        float p0 = __builtin_amdgcn_exp2f(st[ni][0]);
        float p1 = __builtin_amdgcn_exp2f(st[ni][1]);
        float p2 = __builtin_amdgcn_exp2f(st[ni][2]);
        float p3 = __builtin_amdgcn_exp2f(st[ni][3]);
        rs += (p0 + p1) + (p2 + p3);
        uint2 pk;
        pk.x = cvtpk_bf16(p0, p1);
        pk.y = cvtpk_bf16(p2, p3);
        *(uint2*)(pw + rowoff + (((ni * 16 + g4 * 4) * 2) ^ swz)) = pk;
      }
      l_run[mi] += rs;
    }
    #pragma unroll
    for (int ki = 0; ki < 2; ++ki) {
      s16x8 ap[2], bv[4];
      #pragma unroll
      for (int mi = 0; mi < 2; ++mi)
        ap[mi] = *(const s16x8*)(pw + (mi * 16 + li) * 128 +
                                 (((ki * 32 + g4 * 8) * 2) ^ (li7 << 4)));
      #pragma unroll
      for (int di = 0; di < 4; ++di)
        bv[di] = *(const s16x8*)&Vl[(di * 16 + li) * 64 +
                                    (((ki * 64 + g4 * 16) ^ (li7 << 4)) >> 1)];
      #pragma unroll
      for (int mi = 0; mi < 2; ++mi)
        #pragma unroll
        for (int di = 0; di < 4; ++di)
          o[mi][di] = __builtin_amdgcn_mfma_f32_16x16x32_bf16(ap[mi], bv[di], o[mi][di], 0, 0, 0);
    }
    if (t < 15) {
      asm volatile("s_waitcnt vmcnt(0)" ::: "memory");
      __builtin_amdgcn_sched_barrier(0);
    }
    __syncthreads();
  }

  // per-wave epilogue: partial l + unnormalized partial O -> scratch slice ks
  size_t slice = (size_t)(ks * 8 + h) * NTOK;
  #pragma unroll
  for (int mi = 0; mi < 2; ++mi) {
    float v = l_run[mi];
    v += __shfl_xor(v, 16);
    v += __shfl_xor(v, 32);
    if (g4 == 0) lbuf[slice + q0w + mi * 16 + li] = v;
  }
  u16* ob = obuf + (slice + q0w) * 64;
  #pragma unroll
  for (int mi = 0; mi < 2; ++mi)
    #pragma unroll
    for (int di = 0; di < 4; ++di)
      #pragma unroll
      for (int r = 0; r < 4; ++r)
        ob[(size_t)(mi * 16 + g4 * 4 + r) * 64 + di * 16 + li] = f2bf(o[mi][di][r]);
}

extern "C" void kernel_launch(void* const* d_in, const int* in_sizes, int n_in,
                              void* d_out, int out_size, void* d_ws, size_t ws_size,
                              hipStream_t stream) {
  const float* x   = (const float*)d_in[0];
  const float* emb = (const float*)d_in[1];
  const float* Wq  = (const float*)d_in[2];
  const float* Wk  = (const float*)d_in[3];
  const float* Wv  = (const float*)d_in[4];
  const float* g1  = (const float*)d_in[5];
  const float* b1  = (const float*)d_in[6];
  const float* g2  = (const float*)d_in[7];
  const float* b2  = (const float*)d_in[8];
  const float* g3  = (const float*)d_in[9];
  const float* b3  = (const float*)d_in[10];
  const float* Wf1 = (const float*)d_in[11];
  const float* bf1 = (const float*)d_in[12];
  const float* Wf2 = (const float*)d_in[13];
  const float* bf2 = (const float*)d_in[14];
  float* out = (float*)d_out;

  char* ws = (char*)d_ws;
  size_t off = 0;
  auto alloc = [&](size_t bytes) { void* p = ws + off; off += (bytes + 255) & ~255ull; return p; };
  float* xt = (float*)alloc((size_t)NTOK * DMODEL * 4);
  u16* qkin = (u16*)alloc((size_t)NTOK * DCAT * 2);
  u16* hb   = (u16*)alloc((size_t)NTOK * DMODEL * 2);
  u16* r1   = (u16*)alloc((size_t)NTOK * DMODEL * 2);
  u16* qkvh = (u16*)alloc((size_t)3 * NTOK * DMODEL * 2);  // qhd | khd | vT contiguous
  u16* Tqkv = (u16*)alloc((size_t)1536 * DCAT * 2);
  u16* Tf1  = (u16*)alloc((size_t)DMODEL * DMODEL * 2);
  u16* Tf2  = (u16*)alloc((size_t)DMODEL * DMODEL * 2);
  u16* obuf = (u16*)alloc((size_t)4 * NHEAD * NTOK * DHEAD * 2);  // 16 MB
  float* lbuf = (float*)alloc((size_t)4 * NHEAD * NTOK * 4);      // 512 KB
  u16* qhd = qkvh;
  u16* khd = qkvh + (size_t)NTOK * DMODEL;
  u16* vTd = qkvh + (size_t)2 * NTOK * DMODEL;

  wtrans_kernel<<<dim3(9, 8, 5), 256, 0, stream>>>(Wq, Wk, Wv, Wf1, Wf2, Tqkv, Tf1, Tf2);
  lnx_kernel<<<1024, 256, 0, stream>>>(x, g1, b1, xt, qkin);
  lne_kernel<<<1024, 256, 0, stream>>>(emb, g2, b2, qkin);
  gemm_kernel<0><<<dim3(24, 64), 256, 0, stream>>>(qkin, DCAT, Tqkv, DCAT, qkvh, nullptr, nullptr, nullptr);
  attn_kernel<<<1024, 256, 0, stream>>>(qhd, khd, vTd, obuf, lbuf);
  ln3_kernel<<<1024, 256, 0, stream>>>(xt, g3, b3, hb, obuf, lbuf);
  gemm_kernel<3><<<dim3(8, 64), 256, 0, stream>>>(hb, DMODEL, Tf1, DMODEL, r1, nullptr, bf1, nullptr);
  gemm_kernel<4><<<dim3(8, 64), 256, 0, stream>>>(r1, DMODEL, Tf2, DMODEL, nullptr, out, bf2, xt);
}